// Round 15
// baseline (94.072 us; speedup 1.0000x reference)
//
#include <hip/hip_runtime.h>
#include <hip/hip_bf16.h>

// VarFlowLoss on MI355X (gfx950) — round 15
// Register-budget fix: r10-r14's "issue loads early" was silently defeated — live state
// (~180 VGPR) exceeded VGPR_Count (104-128), so the compiler SANK the A-loads to their
// use right after the barrier -> ~900cyc lockstep stall per chunk. This round shrinks
// held state to ~110 VGPR so loads stay hoisted: BM=128, waves 2m x 2oc, acc[4][2]=32,
// A-hold 32 (1 row/wave). A-LDS [4][17][16u] 17KB + B 36KB = 54KB -> 2 blocks/CU.

typedef __attribute__((ext_vector_type(4))) float f32x4;
typedef __attribute__((ext_vector_type(8))) short s16x8;
typedef __attribute__((ext_vector_type(4))) unsigned int u32x4;

#define DEVFN __device__ __forceinline__

DEVFN float bf2f(unsigned short u){
  unsigned int x = ((unsigned int)u) << 16;
  float f; __builtin_memcpy(&f, &x, 4); return f;
}
DEVFN unsigned short f2bf(float f){
  unsigned int x; __builtin_memcpy(&x, &f, 4);
  x += 0x7fffu + ((x >> 16) & 1u);   // RNE
  return (unsigned short)(x >> 16);
}
DEVFN unsigned cvtpk(float lo, float hi){
  unsigned r;
  asm("v_cvt_pk_bf16_f32 %0, %1, %2" : "=v"(r) : "v"(lo), "v"(hi));
  return r;
}

#define ASYNC16(gp, lp) __builtin_amdgcn_global_load_lds( \
    (const __attribute__((address_space(1))) unsigned int*)(gp), \
    (__attribute__((address_space(3))) unsigned int*)(lp), 16, 0, 0)

// ---------------- weights transform ----------------
__global__ void k_weights(const float* __restrict__ Watt, const float* __restrict__ Wpost,
                          unsigned short* __restrict__ WT1, unsigned short* __restrict__ WT2){
  const int t = blockIdx.x * 256 + threadIdx.x;
  const int n1 = 9 * 64 * 256;
  if (t < n1){
    const int tap = t / (64 * 256);
    const int rem = t % (64 * 256);
    const int oc = rem / 256, ic = rem % 256;
    WT1[t] = f2bf(Watt[(oc * 256 + ic) * 9 + tap]);
  }
  const int n2 = 9 * 16 * 64;
  if (t < n2){
    const int tap = t / (16 * 64);
    const int rem = t % (16 * 64);
    const int od = rem / 64, ic = rem % 64;
    const float v = (od < 10) ? Wpost[(od * 64 + ic) * 9 + tap] : 0.0f;
    WT2[t] = f2bf(v);
  }
}

// ---------------- borders: out=0 + patch border log-sums ----------------
__global__ void k_borders(const float* __restrict__ gts, float* __restrict__ S,
                          float* __restrict__ out){
  const int bid = blockIdx.x, tid = threadIdx.x;
  if (bid == 0 && tid == 0) *out = 0.0f;
  __shared__ float slab[4096];
  const int rel = bid;                  // = b*64 + py
  const float* gp = gts + (size_t)rel * 4096;
#pragma unroll
  for (int it = 0; it < 4; ++it){
    const int id = it * 256 + tid;
    *(f32x4*)&slab[id * 4] = *(const f32x4*)&gp[id * 4];
  }
  __syncthreads();
  const int px = tid & 63, border = tid >> 6;   // border wave-uniform
  float s = 0.0f;
#pragma unroll
  for (int i = 0; i < 8; ++i){
    float v;
    if (border == 0)      v = slab[px * 8 + i];
    else if (border == 1) v = slab[7 * 512 + px * 8 + i];
    else if (border == 2) v = slab[i * 512 + px * 8];
    else                  v = slab[i * 512 + px * 8 + 7];
    v = ((v > 0.1f) && (v < 80.0f)) ? v : 0.0f;
    s += __logf(v + 1e-6f);
  }
  S[((size_t)rel * 64 + px) * 4 + border] = s;
}

// ---------------- GEMM1: fused transpose + att conv + sigmoid * depth ----------------
// 1024 blocks (32 b x 32 ytile) x 256 threads (4 waves = 2m x 2oc). BM=128, BK=32.
// A: [4 yy][17 q][16 u] 16B units, u = 4*((g^q)&3) + ((o^(q>>1))&3); q=16 = zero halo.
// B: [576 rows][32 ic] via source-swizzled glds (write phase).
// Per-thread live state ~110 VGPR -> A-loads stay hoisted; compute covers their latency.
__global__ __launch_bounds__(256, 2) void k_gemm1(
    const float* __restrict__ feat,             // NCHW fp32 [B][256][64][64]
    const unsigned short* __restrict__ WT1,     // [9][64][256]
    const float* __restrict__ batt,
    const float* __restrict__ depth,            // NCHW fp32 [B][64][64][64]
    unsigned short* __restrict__ adT)           // [B*4096][64]
{
  __shared__ unsigned short As[4 * 17 * 16 * 8];   // 17408 B
  __shared__ unsigned short Bs[576 * 32];          // 36864 B
  const int t = threadIdx.x;
  const int l = t & 63, wid = t >> 6;
  const int wm = wid & 1, wo = wid >> 1;       // m-half (y-row) / oc-half
  const int b = blockIdx.x >> 5, ytile = blockIdx.x & 31;
  const int y0 = ytile * 2;
  const int fr = l & 15, g = l >> 4;           // x-quad / ic-octet

  f32x4 acc[4][2];
#pragma unroll
  for (int i = 0; i < 4; ++i)
#pragma unroll
    for (int j = 0; j < 2; ++j)
#pragma unroll
      for (int q = 0; q < 4; ++q) acc[i][j][q] = 0.0f;

  // zero the halo quad q=16 once: 64 thr = 4 yy x 16 u
  if (t < 64){
    const int yy = t >> 4, u = t & 15;
    u32x4 z = {0, 0, 0, 0};
    *(u32x4*)&As[((yy * 17 + 16) * 16 + u) * 8] = z;
  }

  // wave wid stages yy=wid: 8 dwordx4 per thread (32 VGPR hold)
  f32x4 hold[8];
  auto loadRow = [&](int c){
    const int yr = y0 - 1 + wid;
    if (yr >= 0 && yr < 64){
      const float* gp = feat + ((size_t)(b * 256 + c * 32 + g * 8)) * 4096
                             + (size_t)yr * 64 + fr * 4;
#pragma unroll
      for (int e = 0; e < 8; ++e) hold[e] = *(const f32x4*)(gp + (size_t)e * 4096);
    } else {
#pragma unroll
      for (int e = 0; e < 8; ++e) hold[e] = f32x4{0.f, 0.f, 0.f, 0.f};
    }
  };
  auto cvtWriteRow = [&](){
#pragma unroll
    for (int o = 0; o < 4; ++o){
      u32x4 pk;
      pk[0] = cvtpk(hold[0][o], hold[1][o]);
      pk[1] = cvtpk(hold[2][o], hold[3][o]);
      pk[2] = cvtpk(hold[4][o], hold[5][o]);
      pk[3] = cvtpk(hold[6][o], hold[7][o]);
      const int u = 4 * ((g ^ fr) & 3) + ((o ^ (fr >> 1)) & 3);
      *(u32x4*)&As[((wid * 17 + fr) * 16 + u) * 8] = pk;
    }
  };
  auto stageB = [&](int c){
#pragma unroll
    for (int it = 0; it < 9; ++it){
      const int idx = it * 256 + t;
      const int row = idx >> 2;
      const int sg = (idx & 3) ^ ((row >> 1) & 3);   // source-slot swizzle
      ASYNC16(WT1 + (size_t)row * 256 + c * 32 + sg * 8, &Bs[(size_t)idx * 8]);
    }
  };
  auto compute = [&](){
    const int slotB = (g ^ ((fr >> 1) & 3)) * 8;
#pragma unroll
    for (int tap = 0; tap < 9; ++tap){
      const int dy = tap / 3 - 1, dx = tap % 3 - 1;
      const int yy = wm + dy + 1;                    // 0..3
      const int rowb = yy * 17 * 16;
      s16x8 af[4], bfr[2];
#pragma unroll
      for (int i = 0; i < 4; ++i){
        const int x = i * 16 + fr + dx;
        const bool valid = (x >= 0) && (x < 64);
        const int xq = valid ? (x >> 2) : 16;
        const int u = valid ? (4 * ((g ^ (x >> 2)) & 3) + (((x & 3) ^ (x >> 3)) & 3))
                            : 4 * g;
        af[i] = *(const s16x8*)&As[(rowb + xq * 16 + u) * 8];
      }
#pragma unroll
      for (int j = 0; j < 2; ++j)
        bfr[j] = *(const s16x8*)&Bs[(tap * 64 + wo * 32 + j * 16 + fr) * 32 + slotB];
#pragma unroll
      for (int i = 0; i < 4; ++i)
#pragma unroll
        for (int j = 0; j < 2; ++j)
          acc[i][j] = __builtin_amdgcn_mfma_f32_16x16x32_bf16(af[i], bfr[j], acc[i][j], 0, 0, 0);
    }
  };

  // prologue: chunk 0
  loadRow(0);
  stageB(0);
  cvtWriteRow();            // waits A-loads once (exposed) 
  __syncthreads();          // drains B(0) glds

  for (int c = 0; c < 8; ++c){
    if (c < 7) loadRow(c + 1);     // 8 dwordx4, held in regs (fits!), covered by compute
    compute();
    __syncthreads();               // vmcnt(0) drain: A-loads covered by ~1000cyc compute
    if (c < 7){
      cvtWriteRow();               // A regs ready
      stageB(c + 1);               // glds; drained at next barrier (~300cyc exposed)
    }
    __syncthreads();               // publish LDS writes
  }

  // epilogue: att = sigmoid(acc + b); adT = att * depth
  const int y = y0 + wm;
#pragma unroll
  for (int j = 0; j < 2; ++j){
    const int oc = wo * 32 + j * 16 + fr;
    const float bb = batt[oc];
    const float* dpt = depth + ((size_t)(b * 64 + oc)) * 4096 + (size_t)y * 64;
    unsigned short* op = adT + ((size_t)(b * 4096 + y * 64)) * 64 + oc;
#pragma unroll
    for (int i = 0; i < 4; ++i){
      const f32x4 dv4 = *(const f32x4*)&dpt[i * 16 + g * 4];
#pragma unroll
      for (int q = 0; q < 4; ++q){
        const int xo = i * 16 + g * 4 + q;
        const float v = acc[i][j][q] + bb;
        const float att = 1.0f / (1.0f + __expf(-v));
        op[(size_t)xo * 64] = f2bf(att * dv4[q]);
      }
    }
  }
}

// ---------------- GEMM2: post conv + fused smooth-L1 loss ----------------
DEVFN float sel4(f32x4 v, int i){
  const float ab = (i & 1) ? v[1] : v[0];
  const float cd = (i & 1) ? v[3] : v[2];
  return (i & 2) ? cd : ab;
}

__global__ __launch_bounds__(512, 2) void k_gemm2(
    const unsigned short* __restrict__ adT,     // [B*4096][64]
    const unsigned short* __restrict__ WT2,     // [9][16][64]
    const float* __restrict__ bpost,
    const f32x4* __restrict__ S,                // [B*4096] {Sn,Ss,Sw,Se}
    float* __restrict__ out)
{
  __shared__ unsigned short As[2][20480];   // 80 KB, source-swizzled
  __shared__ unsigned short Bs[9216];       // full B resident (18 KB), source-swizzled
  __shared__ float ps[8];
  const int t = threadIdx.x;
  const int l = t & 63, w = t >> 6;
  const int b = blockIdx.x >> 3, ytile = blockIdx.x & 7;
  const int y0 = ytile * 8;
  const int fr = l & 15, g = l >> 4;

  f32x4 acc[4];
#pragma unroll
  for (int i = 0; i < 4; ++i)
#pragma unroll
    for (int q = 0; q < 4; ++q) acc[i][q] = 0.0f;

  auto stageA = [&](int c, int d){
#pragma unroll
    for (int it2 = 0; it2 < 5; ++it2){
      const int it = it2 * 2 + (t >> 8);
      const int yy = y0 - 1 + it;
      const int xx = (t >> 2) & 63, icg = t & 3;
      unsigned short* lp = &As[d][(it * 64 + xx) * 32 + icg * 8];
      if (yy >= 0 && yy < 64){
        const int sg = icg ^ ((xx >> 1) & 3);        // source-slot swizzle
        const unsigned short* gp = adT
            + ((size_t)(b * 4096 + yy * 64 + xx)) * 64 + c * 32 + sg * 8;
        ASYNC16(gp, lp);
      } else {
        s16x8 z = {0,0,0,0,0,0,0,0};
        *(s16x8*)lp = z;
      }
    }
  };
  // stage all of B once (144 rows x 128B), 16B slots XOR'd by row&7
#pragma unroll
  for (int it = 0; it < 3; ++it){
    const int idx = it * 512 + t;
    if (idx < 1152){
      const int row = idx >> 3, p = idx & 7;
      const int sg = p ^ (row & 7);
      ASYNC16(WT2 + (size_t)row * 64 + sg * 8, Bs + (size_t)idx * 8);
    }
  }
  stageA(0, 0);
  __syncthreads();

  for (int c = 0; c < 2; ++c){
    if (c == 0) stageA(1, 1);
    const unsigned short* Ab = As[c];
    const int pB = ((c * 4 + g) ^ (fr & 7)) * 8;
    for (int tap = 0; tap < 9; ++tap){
      const int dy = tap / 3 - 1, dx = tap % 3 - 1;
      s16x8 af[4];
#pragma unroll
      for (int i = 0; i < 4; ++i){
        const int xv = i * 16 + fr + dx;
        const bool valid = (xv >= 0) && (xv < 64);
        const int xw = valid ? xv : 0;
        const int slot = (g ^ ((xw >> 1) & 3)) * 8;
        s16x8 v = *(const s16x8*)&Ab[((w + dy + 1) * 64 + xw) * 32 + slot];
        s16x8 z = {0,0,0,0,0,0,0,0};
        af[i] = valid ? v : z;
      }
      const s16x8 bfr = *(const s16x8*)&Bs[(tap * 16 + fr) * 64 + pB];
#pragma unroll
      for (int i = 0; i < 4; ++i)
        acc[i] = __builtin_amdgcn_mfma_f32_16x16x32_bf16(af[i], bfr, acc[i], 0, 0, 0);
    }
    __syncthreads();
  }

  // fused loss epilogue
  const unsigned aPack = (3u<<0)|(1u<<2)|(3u<<4)|(1u<<6)|(2u<<8)|(0u<<10)|(1u<<12)|(3u<<14)|(0u<<16)|(2u<<18);
  const unsigned bPack = (2u<<0)|(0u<<2)|(3u<<4)|(1u<<6)|(2u<<8)|(0u<<10)|(1u<<12)|(3u<<14)|(0u<<16)|(2u<<18);
  float lsum = 0.0f;
  const int y = y0 + w;
  if (fr < 10){
    const int od = fr;
    const int ai = (aPack >> (2 * od)) & 3;
    const int bi = (bPack >> (2 * od)) & 3;
    const bool xshift = (od & 1) == 0;
    const float bp = bpost[od];
#pragma unroll
    for (int i = 0; i < 4; ++i){
#pragma unroll
      for (int q = 0; q < 4; ++q){
        const int xo = i * 16 + g * 4 + q;
        const size_t gm = (size_t)b * 4096 + (size_t)y * 64 + xo;
        const f32x4 sa = S[gm];
        const bool nb = xshift ? (xo < 63) : (y < 63);
        const size_t ga = xshift ? (nb ? gm + 1 : gm) : (nb ? gm + 64 : gm);
        const f32x4 sbv = S[ga];
        const float sbf = nb ? sel4(sbv, bi) : 0.0f;
        const float flow = (sel4(sa, ai) - sbf) * 0.125f;
        const float dv = acc[i][q] + bp - flow;
        const float adv = fabsf(dv);
        lsum += (adv < 0.01f) ? (50.0f * dv * dv) : (adv - 0.005f);
      }
    }
  }
#pragma unroll
  for (int off = 32; off > 0; off >>= 1) lsum += __shfl_down(lsum, off);
  if (l == 0) ps[w] = lsum;
  __syncthreads();
  if (t == 0){
    float s = 0.0f;
#pragma unroll
    for (int i = 0; i < 8; ++i) s += ps[i];
    atomicAdd(out, s * (1.0f / 1310720.0f));
  }
}

// ---------------- launch ----------------
extern "C" void kernel_launch(void* const* d_in, const int* in_sizes, int n_in,
                              void* d_out, int out_size, void* d_ws, size_t ws_size,
                              hipStream_t stream){
  const float* feat  = (const float*)d_in[0];
  const float* depth = (const float*)d_in[1];
  const float* gts   = (const float*)d_in[2];
  const float* Watt  = (const float*)d_in[3];
  const float* batt  = (const float*)d_in[4];
  const float* Wpost = (const float*)d_in[5];
  const float* bpost = (const float*)d_in[6];
  float* out = (float*)d_out;
  char* ws = (char*)d_ws;

  unsigned short* adT = (unsigned short*)ws;                       // 16777216 B
  unsigned short* WT1 = (unsigned short*)(ws + 16777216);          // 294912 B
  unsigned short* WT2 = (unsigned short*)(ws + 16777216 + 294912); // 18432 B
  float*          S   = (float*)(ws + 16777216 + 294912 + 18432);  // 2097152 B

  k_weights<<<576, 256, 0, stream>>>(Watt, Wpost, WT1, WT2);
  k_gemm1<<<1024, 256, 0, stream>>>(feat, WT1, batt, depth, adT);
  k_borders<<<2048, 256, 0, stream>>>(gts, S, out);
  k_gemm2<<<256, 512, 0, stream>>>(adT, WT2, bpost, (const f32x4*)S, out);
}

// Round 16
// 75.935 us; speedup vs baseline: 1.2389x; 1.2389x over previous
//
#include <hip/hip_runtime.h>
#include <hip/hip_bf16.h>

// VarFlowLoss on MI355X (gfx950) — round 16
// r13 base (best gemm1) + additive levers:
//  - setprio(1) around MFMA taps (T5; 2 blocks/CU = phase diversity)
//  - B-glds issued BEFORE cvt/ds_write in chunk tail (drain gets ~300cyc cover)
//  - XCD-aware bijective block swizzle (512%8==0)
//  - fused k_prep (out=0 + weights + borders), launched first

typedef __attribute__((ext_vector_type(4))) float f32x4;
typedef __attribute__((ext_vector_type(8))) short s16x8;
typedef __attribute__((ext_vector_type(4))) unsigned int u32x4;

#define DEVFN __device__ __forceinline__

DEVFN float bf2f(unsigned short u){
  unsigned int x = ((unsigned int)u) << 16;
  float f; __builtin_memcpy(&f, &x, 4); return f;
}
DEVFN unsigned short f2bf(float f){
  unsigned int x; __builtin_memcpy(&x, &f, 4);
  x += 0x7fffu + ((x >> 16) & 1u);   // RNE
  return (unsigned short)(x >> 16);
}
DEVFN unsigned cvtpk(float lo, float hi){
  unsigned r;
  asm("v_cvt_pk_bf16_f32 %0, %1, %2" : "=v"(r) : "v"(lo), "v"(hi));
  return r;
}

#define ASYNC16(gp, lp) __builtin_amdgcn_global_load_lds( \
    (const __attribute__((address_space(1))) unsigned int*)(gp), \
    (__attribute__((address_space(3))) unsigned int*)(lp), 16, 0, 0)

// ---------------- prep: out=0 + weights + borders ----------------
__global__ void k_prep(const float* __restrict__ Watt, const float* __restrict__ Wpost,
                       const float* __restrict__ gts,
                       unsigned short* __restrict__ WT1, unsigned short* __restrict__ WT2,
                       float* __restrict__ S, float* __restrict__ out){
  const int bid = blockIdx.x, tid = threadIdx.x;
  if (bid == 0 && tid == 0) *out = 0.0f;
  if (bid < 576){
    const int t = bid * 256 + tid;
    const int n1 = 9 * 64 * 256;
    if (t < n1){
      const int tap = t / (64 * 256);
      const int rem = t % (64 * 256);
      const int oc = rem / 256, ic = rem % 256;
      WT1[t] = f2bf(Watt[(oc * 256 + ic) * 9 + tap]);
    }
    const int n2 = 9 * 16 * 64;
    if (t < n2){
      const int tap = t / (16 * 64);
      const int rem = t % (16 * 64);
      const int od = rem / 64, ic = rem % 64;
      const float v = (od < 10) ? Wpost[(od * 64 + ic) * 9 + tap] : 0.0f;
      WT2[t] = f2bf(v);
    }
    return;
  }
  // borders: one block per (b, py) 8-row slab
  __shared__ float slab[4096];
  const int rel = bid - 576;            // = b*64 + py
  const float* gp = gts + (size_t)rel * 4096;
#pragma unroll
  for (int it = 0; it < 4; ++it){
    const int id = it * 256 + tid;
    *(f32x4*)&slab[id * 4] = *(const f32x4*)&gp[id * 4];
  }
  __syncthreads();
  const int px = tid & 63, border = tid >> 6;   // border wave-uniform
  float s = 0.0f;
#pragma unroll
  for (int i = 0; i < 8; ++i){
    float v;
    if (border == 0)      v = slab[px * 8 + i];
    else if (border == 1) v = slab[7 * 512 + px * 8 + i];
    else if (border == 2) v = slab[i * 512 + px * 8];
    else                  v = slab[i * 512 + px * 8 + 7];
    v = ((v > 0.1f) && (v < 80.0f)) ? v : 0.0f;
    s += __logf(v + 1e-6f);
  }
  S[((size_t)rel * 64 + px) * 4 + border] = s;
}

// ---------------- GEMM1: fused transpose + att conv + sigmoid * depth ----------------
// 512 blocks x 256 threads (4 waves). BM=256 (4 y-rows), BK=32, 8 chunks.
// A: [6 yy][17 q][16 u] 16B units (26.1KB), u=(4g+o)^fr write / ^(x>>2) read; q=16 halo.
// B: [576 rows][32 ic] source-swizzled glds, issued FIRST in the tail phase.
__global__ __launch_bounds__(256, 2) void k_gemm1(
    const float* __restrict__ feat,             // NCHW fp32 [B][256][64][64]
    const unsigned short* __restrict__ WT1,     // [9][64][256]
    const float* __restrict__ batt,
    const float* __restrict__ depth,            // NCHW fp32 [B][64][64][64]
    unsigned short* __restrict__ adT)           // [B*4096][64]
{
  __shared__ unsigned short As[6 * 17 * 16 * 8];   // 26112 B
  __shared__ unsigned short Bs[576 * 32];          // 36864 B
  const int t = threadIdx.x;
  const int l = t & 63, w = t >> 6;
  // XCD-aware bijective swizzle: 512 blocks, 8 XCDs
  const int bid = (blockIdx.x & 7) * 64 + (blockIdx.x >> 3);
  const int b = bid >> 4, ytile = bid & 15;
  const int y0 = ytile * 4;
  const int fr = l & 15, g = l >> 4;           // x-quad / ic-octet

  f32x4 acc[4][4];
#pragma unroll
  for (int i = 0; i < 4; ++i)
#pragma unroll
    for (int j = 0; j < 4; ++j)
#pragma unroll
      for (int q = 0; q < 4; ++q) acc[i][j][q] = 0.0f;

  // zero the halo quad q=16 (x-image-border) once: 96 thr = 6 yy x 16 u
  if (t < 96){
    const int yy = t >> 4, sp = t & 15;
    u32x4 z = {0, 0, 0, 0};
    *(u32x4*)&As[((yy * 17 + 16) * 16 + sp) * 8] = z;
  }

  auto loadRow = [&](int c, int yy, f32x4* v){
    const int yr = y0 - 1 + yy;
    if (yr >= 0 && yr < 64){
      const float* gp = feat + ((size_t)(b * 256 + c * 32 + g * 8)) * 4096
                             + (size_t)yr * 64 + fr * 4;
#pragma unroll
      for (int e = 0; e < 8; ++e) v[e] = *(const f32x4*)(gp + (size_t)e * 4096);
    } else {
#pragma unroll
      for (int e = 0; e < 8; ++e) v[e] = f32x4{0.f, 0.f, 0.f, 0.f};
    }
  };
  auto cvtWriteRow = [&](int yy, const f32x4* v){
#pragma unroll
    for (int o = 0; o < 4; ++o){
      u32x4 pk;
      pk[0] = cvtpk(v[0][o], v[1][o]);
      pk[1] = cvtpk(v[2][o], v[3][o]);
      pk[2] = cvtpk(v[4][o], v[5][o]);
      pk[3] = cvtpk(v[6][o], v[7][o]);
      const int sp = (4 * g + o) ^ fr;
      *(u32x4*)&As[((yy * 17 + fr) * 16 + sp) * 8] = pk;
    }
  };
  auto stageB = [&](int c){
#pragma unroll
    for (int it = 0; it < 9; ++it){
      const int idx = it * 256 + t;
      const int row = idx >> 2;
      const int sg = (idx & 3) ^ ((row >> 1) & 3);   // source-slot swizzle
      ASYNC16(WT1 + (size_t)row * 256 + c * 32 + sg * 8, &Bs[(size_t)idx * 8]);
    }
  };
  auto compute = [&](){
    const int slotB = (g ^ ((fr >> 1) & 3)) * 8;
    __builtin_amdgcn_s_setprio(1);
#pragma unroll
    for (int tap = 0; tap < 9; ++tap){
      const int dy = tap / 3 - 1, dx = tap % 3 - 1;
      const int yy = w + dy + 1;
      const int rowb = yy * 17 * 16;
      s16x8 af[4], bfr[4];
#pragma unroll
      for (int i = 0; i < 4; ++i){
        const int x = i * 16 + fr + dx;
        const bool valid = (x >= 0) && (x < 64);
        const int xq = valid ? (x >> 2) : 16;
        const int sp = valid ? ((4 * g + (x & 3)) ^ (x >> 2)) : 4 * g;
        af[i] = *(const s16x8*)&As[(rowb + xq * 16 + sp) * 8];
      }
#pragma unroll
      for (int j = 0; j < 4; ++j)
        bfr[j] = *(const s16x8*)&Bs[(tap * 64 + j * 16 + fr) * 32 + slotB];
#pragma unroll
      for (int i = 0; i < 4; ++i)
#pragma unroll
        for (int j = 0; j < 4; ++j)
          acc[i][j] = __builtin_amdgcn_mfma_f32_16x16x32_bf16(af[i], bfr[j], acc[i][j], 0, 0, 0);
    }
    __builtin_amdgcn_s_setprio(0);
  };

  // prologue: chunk 0
  f32x4 r0[8], r1[8];
  loadRow(0, w, r0);
  if (w < 2) loadRow(0, 4 + w, r1);
  stageB(0);
  cvtWriteRow(w, r0);
  if (w < 2) cvtWriteRow(4 + w, r1);
  __syncthreads();

  for (int c = 0; c < 8; ++c){
    if (c < 7){
      loadRow(c + 1, w, r0);               // issued early; compute covers latency
      if (w < 2) loadRow(c + 1, 4 + w, r1);
    }
    compute();
    __syncthreads();                       // A/B reads done; A-loads complete by now
    if (c < 7){
      stageB(c + 1);                       // glds first: cvt/ds_write covers the drain
      cvtWriteRow(w, r0);                  // waits only on (completed) A-loads
      if (w < 2) cvtWriteRow(4 + w, r1);
    }
    __syncthreads();                       // B glds + LDS writes visible
  }

  // epilogue: att = sigmoid(acc + b); adT = att * depth
  const int y = y0 + w;
#pragma unroll
  for (int j = 0; j < 4; ++j){
    const int oc = j * 16 + fr;
    const float bb = batt[oc];
    const float* dpt = depth + ((size_t)(b * 64 + oc)) * 4096 + (size_t)y * 64;
    unsigned short* op = adT + ((size_t)(b * 4096 + y * 64)) * 64 + oc;
#pragma unroll
    for (int i = 0; i < 4; ++i){
      const f32x4 dv4 = *(const f32x4*)&dpt[i * 16 + g * 4];
#pragma unroll
      for (int q = 0; q < 4; ++q){
        const int xo = i * 16 + g * 4 + q;
        const float v = acc[i][j][q] + bb;
        const float att = 1.0f / (1.0f + __expf(-v));
        op[(size_t)xo * 64] = f2bf(att * dv4[q]);
      }
    }
  }
}

// ---------------- GEMM2: post conv + fused smooth-L1 loss ----------------
DEVFN float sel4(f32x4 v, int i){
  const float ab = (i & 1) ? v[1] : v[0];
  const float cd = (i & 1) ? v[3] : v[2];
  return (i & 2) ? cd : ab;
}

__global__ __launch_bounds__(512, 2) void k_gemm2(
    const unsigned short* __restrict__ adT,     // [B*4096][64]
    const unsigned short* __restrict__ WT2,     // [9][16][64]
    const float* __restrict__ bpost,
    const f32x4* __restrict__ S,                // [B*4096] {Sn,Ss,Sw,Se}
    float* __restrict__ out)
{
  __shared__ unsigned short As[2][20480];   // 80 KB, source-swizzled
  __shared__ unsigned short Bs[9216];       // full B resident (18 KB), source-swizzled
  __shared__ float ps[8];
  const int t = threadIdx.x;
  const int l = t & 63, w = t >> 6;
  const int b = blockIdx.x >> 3, ytile = blockIdx.x & 7;
  const int y0 = ytile * 8;
  const int fr = l & 15, g = l >> 4;

  f32x4 acc[4];
#pragma unroll
  for (int i = 0; i < 4; ++i)
#pragma unroll
    for (int q = 0; q < 4; ++q) acc[i][q] = 0.0f;

  auto stageA = [&](int c, int d){
#pragma unroll
    for (int it2 = 0; it2 < 5; ++it2){
      const int it = it2 * 2 + (t >> 8);
      const int yy = y0 - 1 + it;
      const int xx = (t >> 2) & 63, icg = t & 3;
      unsigned short* lp = &As[d][(it * 64 + xx) * 32 + icg * 8];
      if (yy >= 0 && yy < 64){
        const int sg = icg ^ ((xx >> 1) & 3);        // source-slot swizzle
        const unsigned short* gp = adT
            + ((size_t)(b * 4096 + yy * 64 + xx)) * 64 + c * 32 + sg * 8;
        ASYNC16(gp, lp);
      } else {
        s16x8 z = {0,0,0,0,0,0,0,0};
        *(s16x8*)lp = z;
      }
    }
  };
  // stage all of B once (144 rows x 128B), 16B slots XOR'd by row&7
#pragma unroll
  for (int it = 0; it < 3; ++it){
    const int idx = it * 512 + t;
    if (idx < 1152){
      const int row = idx >> 3, p = idx & 7;
      const int sg = p ^ (row & 7);
      ASYNC16(WT2 + (size_t)row * 64 + sg * 8, Bs + (size_t)idx * 8);
    }
  }
  stageA(0, 0);
  __syncthreads();

  for (int c = 0; c < 2; ++c){
    if (c == 0) stageA(1, 1);
    const unsigned short* Ab = As[c];
    const int pB = ((c * 4 + g) ^ (fr & 7)) * 8;
    for (int tap = 0; tap < 9; ++tap){
      const int dy = tap / 3 - 1, dx = tap % 3 - 1;
      s16x8 af[4];
#pragma unroll
      for (int i = 0; i < 4; ++i){
        const int xv = i * 16 + fr + dx;
        const bool valid = (xv >= 0) && (xv < 64);
        const int xw = valid ? xv : 0;
        const int slot = (g ^ ((xw >> 1) & 3)) * 8;
        s16x8 v = *(const s16x8*)&Ab[((w + dy + 1) * 64 + xw) * 32 + slot];
        s16x8 z = {0,0,0,0,0,0,0,0};
        af[i] = valid ? v : z;
      }
      const s16x8 bfr = *(const s16x8*)&Bs[(tap * 16 + fr) * 64 + pB];
#pragma unroll
      for (int i = 0; i < 4; ++i)
        acc[i] = __builtin_amdgcn_mfma_f32_16x16x32_bf16(af[i], bfr, acc[i], 0, 0, 0);
    }
    __syncthreads();
  }

  // fused loss epilogue
  const unsigned aPack = (3u<<0)|(1u<<2)|(3u<<4)|(1u<<6)|(2u<<8)|(0u<<10)|(1u<<12)|(3u<<14)|(0u<<16)|(2u<<18);
  const unsigned bPack = (2u<<0)|(0u<<2)|(3u<<4)|(1u<<6)|(2u<<8)|(0u<<10)|(1u<<12)|(3u<<14)|(0u<<16)|(2u<<18);
  float lsum = 0.0f;
  const int y = y0 + w;
  if (fr < 10){
    const int od = fr;
    const int ai = (aPack >> (2 * od)) & 3;
    const int bi = (bPack >> (2 * od)) & 3;
    const bool xshift = (od & 1) == 0;
    const float bp = bpost[od];
#pragma unroll
    for (int i = 0; i < 4; ++i){
#pragma unroll
      for (int q = 0; q < 4; ++q){
        const int xo = i * 16 + g * 4 + q;
        const size_t gm = (size_t)b * 4096 + (size_t)y * 64 + xo;
        const f32x4 sa = S[gm];
        const bool nb = xshift ? (xo < 63) : (y < 63);
        const size_t ga = xshift ? (nb ? gm + 1 : gm) : (nb ? gm + 64 : gm);
        const f32x4 sbv = S[ga];
        const float sbf = nb ? sel4(sbv, bi) : 0.0f;
        const float flow = (sel4(sa, ai) - sbf) * 0.125f;
        const float dv = acc[i][q] + bp - flow;
        const float adv = fabsf(dv);
        lsum += (adv < 0.01f) ? (50.0f * dv * dv) : (adv - 0.005f);
      }
    }
  }
#pragma unroll
  for (int off = 32; off > 0; off >>= 1) lsum += __shfl_down(lsum, off);
  if (l == 0) ps[w] = lsum;
  __syncthreads();
  if (t == 0){
    float s = 0.0f;
#pragma unroll
    for (int i = 0; i < 8; ++i) s += ps[i];
    atomicAdd(out, s * (1.0f / 1310720.0f));
  }
}

// ---------------- launch ----------------
extern "C" void kernel_launch(void* const* d_in, const int* in_sizes, int n_in,
                              void* d_out, int out_size, void* d_ws, size_t ws_size,
                              hipStream_t stream){
  const float* feat  = (const float*)d_in[0];
  const float* depth = (const float*)d_in[1];
  const float* gts   = (const float*)d_in[2];
  const float* Watt  = (const float*)d_in[3];
  const float* batt  = (const float*)d_in[4];
  const float* Wpost = (const float*)d_in[5];
  const float* bpost = (const float*)d_in[6];
  float* out = (float*)d_out;
  char* ws = (char*)d_ws;

  unsigned short* adT = (unsigned short*)ws;                       // 16777216 B
  unsigned short* WT1 = (unsigned short*)(ws + 16777216);          // 294912 B
  unsigned short* WT2 = (unsigned short*)(ws + 16777216 + 294912); // 18432 B
  float*          S   = (float*)(ws + 16777216 + 294912 + 18432);  // 2097152 B

  k_prep<<<576 + 2048, 256, 0, stream>>>(Watt, Wpost, gts, WT1, WT2, S, out);
  k_gemm1<<<512, 256, 0, stream>>>(feat, WT1, batt, depth, adT);
  k_gemm2<<<256, 512, 0, stream>>>(adT, WT2, bpost, (const f32x4*)S, out);
}